// Round 1
// baseline (140.973 us; speedup 1.0000x reference)
//
#include <hip/hip_runtime.h>

// ---------------- workspace float offsets ----------------
#define WS_WQC  0
#define WS_WKC  16384
#define WS_WVC  32768
#define WS_MOW  49152
#define WS_G    65536
#define WS_GS   69632
#define WS_GD   71680
#define WS_G0   73728
#define WS_GS0  73792
#define WS_GD0  73824
#define WS_FSP  73856
#define WS_FDV  77952
#define WS_FHID 82048
#define WS_FB   90240
// total floats used: 90368 + 128 = 90496 (~354 KB)

// P1: Wqc = wq@w_iq, Wkc = wk@w_ik, Wvc = wv@w_iv, Mow = mha_out_w@out_w
__global__ __launch_bounds__(128) void precompute1(
    const float* __restrict__ wq, const float* __restrict__ wk,
    const float* __restrict__ wv, const float* __restrict__ in_proj_w,
    const float* __restrict__ mha_out_w, const float* __restrict__ out_w,
    float* __restrict__ ws)
{
    __shared__ float arow[128];
    const int mat = blockIdx.x & 3;
    const int r   = blockIdx.x >> 2;
    const int tid = threadIdx.x;
    const float* A; const float* Bm; int ldb; float* C;
    if (mat == 0)      { A = wq;        Bm = in_proj_w;       ldb = 384; C = ws + WS_WQC; }
    else if (mat == 1) { A = wk;        Bm = in_proj_w + 128; ldb = 384; C = ws + WS_WKC; }
    else if (mat == 2) { A = wv;        Bm = in_proj_w + 256; ldb = 384; C = ws + WS_WVC; }
    else               { A = mha_out_w; Bm = out_w;           ldb = 128; C = ws + WS_MOW; }
    arow[tid] = A[r * 128 + tid];
    __syncthreads();
    float acc = 0.f;
    #pragma unroll 8
    for (int d = 0; d < 128; ++d) acc = fmaf(arow[d], Bm[d * ldb + tid], acc);
    C[r * 128 + tid] = acc;
}

// P2: derived tensors
__global__ __launch_bounds__(128) void precompute2(
    const float* __restrict__ b_sp, const float* __restrict__ b_vel,
    const float* __restrict__ in_proj_b, const float* __restrict__ mha_out_b,
    const float* __restrict__ out_w, const float* __restrict__ out_b,
    float* __restrict__ ws)
{
    const float* Wqc = ws + WS_WQC;
    const float* Wkc = ws + WS_WKC;
    const float* Wvc = ws + WS_WVC;
    const float* Mow = ws + WS_MOW;
    const int bid = blockIdx.x, tid = threadIdx.x;
    __shared__ float sa[256];

    if (bid < 64) {
        // G[r][c] = Wqc[32+r] . Wkc[32+c]; Gs[r][s] = Wqc[32+r] . Wkc[s]; Gd: Wkc[96+s]
        const int r = bid;
        sa[tid] = Wqc[(32 + r) * 128 + tid];
        __syncthreads();
        const float* brow; float* dst;
        if (tid < 64)      { brow = Wkc + (32 + tid) * 128;      dst = ws + WS_G  + r * 64 + tid; }
        else if (tid < 96) { brow = Wkc + (tid - 64) * 128;      dst = ws + WS_GS + r * 32 + (tid - 64); }
        else               { brow = Wkc + (96 + tid - 96) * 128; dst = ws + WS_GD + r * 32 + (tid - 96); }
        float acc = 0.f;
        #pragma unroll 8
        for (int d = 0; d < 128; ++d) acc = fmaf(sa[d], brow[d], acc);
        *dst = acc;
    } else if (bid < 96) {
        // Fsp[s][o] = Wvc[s] @ Mow col o ; Fdv[s][o] = Wvc[96+s] @ Mow col o
        const int s = bid - 64;
        sa[tid]       = Wvc[s * 128 + tid];
        sa[128 + tid] = Wvc[(96 + s) * 128 + tid];
        __syncthreads();
        float a1 = 0.f, a2 = 0.f;
        #pragma unroll 8
        for (int m = 0; m < 128; ++m) {
            const float mo = Mow[m * 128 + tid];
            a1 = fmaf(sa[m], mo, a1);
            a2 = fmaf(sa[128 + m], mo, a2);
        }
        ws[WS_FSP + s * 128 + tid] = a1;
        ws[WS_FDV + s * 128 + tid] = a2;
    } else if (bid < 160) {
        // Fhid[c][o] = Wvc[32+c] @ Mow col o
        const int c = bid - 96;
        sa[tid] = Wvc[(32 + c) * 128 + tid];
        __syncthreads();
        float acc = 0.f;
        #pragma unroll 8
        for (int m = 0; m < 128; ++m) acc = fmaf(sa[m], Mow[m * 128 + tid], acc);
        ws[WS_FHID + c * 128 + tid] = acc;
    } else if (bid == 160) {
        // fb[o] = out_b[o] + b_iv @ Mow col o + mha_out_b @ out_w col o
        float acc = out_b[tid];
        #pragma unroll 8
        for (int m = 0; m < 128; ++m) {
            acc = fmaf(in_proj_b[256 + m], Mow[m * 128 + tid], acc);
            acc = fmaf(mha_out_b[m], out_w[m * 128 + tid], acc);
        }
        ws[WS_FB + tid] = acc;
    } else {
        // q_const then g0/gs0/gd0
        float qc = in_proj_b[tid];  // b_iq
        #pragma unroll 4
        for (int s = 0; s < 32; ++s) {
            qc = fmaf(fmaxf(b_sp[s], 0.f),  Wqc[s * 128 + tid], qc);
            qc = fmaf(fmaxf(b_vel[s], 0.f), Wqc[(96 + s) * 128 + tid], qc);
        }
        sa[tid] = qc;
        __syncthreads();
        const float* brow; float* dst;
        if (tid < 64)      { brow = Wkc + (32 + tid) * 128;      dst = ws + WS_G0  + tid; }
        else if (tid < 96) { brow = Wkc + (tid - 64) * 128;      dst = ws + WS_GS0 + (tid - 64); }
        else               { brow = Wkc + (96 + tid - 96) * 128; dst = ws + WS_GD0 + (tid - 96); }
        float acc = 0.f;
        #pragma unroll 8
        for (int d = 0; d < 128; ++d) acc = fmaf(sa[d], brow[d], acc);
        *dst = acc;
    }
}

// Main kernel: 2 blocks per batch (32 query rows each), 256 threads.
__global__ __launch_bounds__(256) void attn_main(
    const float* __restrict__ hs, const float* __restrict__ obs1,
    const float* __restrict__ obs2,
    const float* __restrict__ w_sp, const float* __restrict__ b_sp,
    const float* __restrict__ w_vel, const float* __restrict__ b_vel,
    const float* __restrict__ w_hid, const float* __restrict__ b_hid,
    const float* __restrict__ ws, float* __restrict__ out)
{
    const int tid  = threadIdx.x;
    const int lane = tid & 63;
    const int b    = blockIdx.x >> 1;
    const int i0   = (blockIdx.x & 1) * 32;

    const float* Gm   = ws + WS_G;
    const float* Gs   = ws + WS_GS;
    const float* Gd   = ws + WS_GD;
    const float* g0v  = ws + WS_G0;
    const float* gs0v = ws + WS_GS0;
    const float* gd0v = ws + WS_GD0;
    const float* Fsp  = ws + WS_FSP;
    const float* Fdv  = ws + WS_FDV;
    const float* Fhid = ws + WS_FHID;
    const float* fbv  = ws + WS_FB;

    __shared__ __align__(16) float sA[8192];    // 32 KB, multi-purpose
    __shared__ __align__(16) float s_hid[4096]; // hid, 64x64 row-major
    __shared__ __align__(16) float s_w[192];    // wsp0|wsp1|wvl0|wvl1|bsp|bvl
    __shared__ __align__(16) float s_obs[256];  // per j: {o2x,o2y,vx,vy}

    float* const s_t    = sA;          // 32x64: t -> qh -> scores -> attn
    float* const s_qs   = sA + 2048;   // 32x32
    float* const s_qd   = sA + 3072;   // 32x32
    float* const s_hidT = sA + 4096;   // 64x64 (dead after phase 4)
    float* const s_ssp  = sA + 4096;   // 32x32 (phase 6+)
    float* const s_sdv  = sA + 5120;   // 32x32
    float* const s_ah   = sA + 6144;   // 32x64

    // ---- phase 0: small weights + obs staging ----
    if (tid < 192) {
        float v;
        if (tid < 64)       v = w_sp[tid];
        else if (tid < 128) v = w_vel[tid - 64];
        else if (tid < 160) v = b_sp[tid - 128];
        else                v = b_vel[tid - 160];
        s_w[tid] = v;
    }
    if (tid < 64) {
        const int g = b * 64 + tid;
        const float ox = obs2[g * 2 + 0];
        const float oy = obs2[g * 2 + 1];
        const float vx = ox - obs1[g * 2 + 0];
        const float vy = oy - obs1[g * 2 + 1];
        *(float4*)&s_obs[tid * 4] = make_float4(ox, oy, vx, vy);
    }

    // ---- phase 2: hid = relu(hs @ w_hid + b_hid), full 64x64, two halves ----
    for (int h = 0; h < 2; ++h) {
        const float4* srcH = (const float4*)(hs + b * 8192 + h * 4096);
        float4* dstA = (float4*)sA;
        #pragma unroll
        for (int k = tid; k < 1024; k += 256) dstA[k] = srcH[k];
        __syncthreads();
        {
            const int ty = tid >> 4, tx = tid & 15;  // rows 2ty(+1), cols 4tx..4tx+3
            float a0c[4] = {0,0,0,0}, a1c[4] = {0,0,0,0};
            for (int d0 = 0; d0 < 128; d0 += 4) {
                const float4 a0 = *(const float4*)&sA[(2*ty+0)*128 + d0];
                const float4 a1 = *(const float4*)&sA[(2*ty+1)*128 + d0];
                const float* a0p = (const float*)&a0;
                const float* a1p = (const float*)&a1;
                #pragma unroll
                for (int dd = 0; dd < 4; ++dd) {
                    const float4 w4 = *(const float4*)&w_hid[(d0+dd)*64 + 4*tx];
                    a0c[0] = fmaf(a0p[dd], w4.x, a0c[0]);
                    a0c[1] = fmaf(a0p[dd], w4.y, a0c[1]);
                    a0c[2] = fmaf(a0p[dd], w4.z, a0c[2]);
                    a0c[3] = fmaf(a0p[dd], w4.w, a0c[3]);
                    a1c[0] = fmaf(a1p[dd], w4.x, a1c[0]);
                    a1c[1] = fmaf(a1p[dd], w4.y, a1c[1]);
                    a1c[2] = fmaf(a1p[dd], w4.z, a1c[2]);
                    a1c[3] = fmaf(a1p[dd], w4.w, a1c[3]);
                }
            }
            const float4 bh = *(const float4*)&b_hid[4*tx];
            float v0[4], v1[4];
            v0[0] = fmaxf(a0c[0] + bh.x, 0.f); v0[1] = fmaxf(a0c[1] + bh.y, 0.f);
            v0[2] = fmaxf(a0c[2] + bh.z, 0.f); v0[3] = fmaxf(a0c[3] + bh.w, 0.f);
            v1[0] = fmaxf(a1c[0] + bh.x, 0.f); v1[1] = fmaxf(a1c[1] + bh.y, 0.f);
            v1[2] = fmaxf(a1c[2] + bh.z, 0.f); v1[3] = fmaxf(a1c[3] + bh.w, 0.f);
            const int r0 = 32*h + 2*ty;
            *(float4*)&s_hid[(r0+0)*64 + 4*tx] = make_float4(v0[0], v0[1], v0[2], v0[3]);
            *(float4*)&s_hid[(r0+1)*64 + 4*tx] = make_float4(v1[0], v1[1], v1[2], v1[3]);
            #pragma unroll
            for (int cc = 0; cc < 4; ++cc)
                *(float2*)&s_hidT[(4*tx+cc)*64 + r0] = make_float2(v0[cc], v1[cc]);
        }
        __syncthreads();
    }

    // ---- phase 3: t = hid[i0..]@G + g0 ; qs/qd = hid[i0..]@Gs/Gd + gs0/gd0 ----
    {
        const int ty = tid >> 4, tx = tid & 15;
        const int r0 = i0 + 2*ty;
        {
            const float4 gb = *(const float4*)&g0v[4*tx];
            float t0[4] = {gb.x, gb.y, gb.z, gb.w};
            float t1[4] = {gb.x, gb.y, gb.z, gb.w};
            for (int k0 = 0; k0 < 64; k0 += 4) {
                const float4 a0 = *(const float4*)&s_hid[(r0+0)*64 + k0];
                const float4 a1 = *(const float4*)&s_hid[(r0+1)*64 + k0];
                const float* a0p = (const float*)&a0;
                const float* a1p = (const float*)&a1;
                #pragma unroll
                for (int kk = 0; kk < 4; ++kk) {
                    const float4 g4 = *(const float4*)&Gm[(k0+kk)*64 + 4*tx];
                    t0[0] = fmaf(a0p[kk], g4.x, t0[0]); t0[1] = fmaf(a0p[kk], g4.y, t0[1]);
                    t0[2] = fmaf(a0p[kk], g4.z, t0[2]); t0[3] = fmaf(a0p[kk], g4.w, t0[3]);
                    t1[0] = fmaf(a1p[kk], g4.x, t1[0]); t1[1] = fmaf(a1p[kk], g4.y, t1[1]);
                    t1[2] = fmaf(a1p[kk], g4.z, t1[2]); t1[3] = fmaf(a1p[kk], g4.w, t1[3]);
                }
            }
            *(float4*)&s_t[(2*ty+0)*64 + 4*tx] = make_float4(t0[0], t0[1], t0[2], t0[3]);
            *(float4*)&s_t[(2*ty+1)*64 + 4*tx] = make_float4(t1[0], t1[1], t1[2], t1[3]);
        }
        {
            const float* Bm  = (tx < 8) ? Gs : Gd;
            const float* bm0 = (tx < 8) ? gs0v : gd0v;
            float* dstm      = (tx < 8) ? s_qs : s_qd;
            const int nc = (tx & 7) * 4;
            const float4 bb = *(const float4*)&bm0[nc];
            float q0[4] = {bb.x, bb.y, bb.z, bb.w};
            float q1[4] = {bb.x, bb.y, bb.z, bb.w};
            for (int k0 = 0; k0 < 64; k0 += 4) {
                const float4 a0 = *(const float4*)&s_hid[(r0+0)*64 + k0];
                const float4 a1 = *(const float4*)&s_hid[(r0+1)*64 + k0];
                const float* a0p = (const float*)&a0;
                const float* a1p = (const float*)&a1;
                #pragma unroll
                for (int kk = 0; kk < 4; ++kk) {
                    const float4 g4 = *(const float4*)&Bm[(k0+kk)*32 + nc];
                    q0[0] = fmaf(a0p[kk], g4.x, q0[0]); q0[1] = fmaf(a0p[kk], g4.y, q0[1]);
                    q0[2] = fmaf(a0p[kk], g4.z, q0[2]); q0[3] = fmaf(a0p[kk], g4.w, q0[3]);
                    q1[0] = fmaf(a1p[kk], g4.x, q1[0]); q1[1] = fmaf(a1p[kk], g4.y, q1[1]);
                    q1[2] = fmaf(a1p[kk], g4.z, q1[2]); q1[3] = fmaf(a1p[kk], g4.w, q1[3]);
                }
            }
            *(float4*)&dstm[(2*ty+0)*32 + nc] = make_float4(q0[0], q0[1], q0[2], q0[3]);
            *(float4*)&dstm[(2*ty+1)*32 + nc] = make_float4(q1[0], q1[1], q1[2], q1[3]);
        }
    }
    __syncthreads();

    // ---- phase 4: qh = t @ hid^T (via hidT), written over s_t ----
    {
        const int ty = tid >> 4, tx = tid & 15;
        float q0[4] = {0,0,0,0}, q1[4] = {0,0,0,0};
        for (int c0 = 0; c0 < 64; c0 += 4) {
            const float4 t40 = *(const float4*)&s_t[(2*ty+0)*64 + c0];
            const float4 t41 = *(const float4*)&s_t[(2*ty+1)*64 + c0];
            const float* t0p = (const float*)&t40;
            const float* t1p = (const float*)&t41;
            #pragma unroll
            for (int cc = 0; cc < 4; ++cc) {
                const float4 h4 = *(const float4*)&s_hidT[(c0+cc)*64 + 4*tx];
                q0[0] = fmaf(t0p[cc], h4.x, q0[0]); q0[1] = fmaf(t0p[cc], h4.y, q0[1]);
                q0[2] = fmaf(t0p[cc], h4.z, q0[2]); q0[3] = fmaf(t0p[cc], h4.w, q0[3]);
                q1[0] = fmaf(t1p[cc], h4.x, q1[0]); q1[1] = fmaf(t1p[cc], h4.y, q1[1]);
                q1[2] = fmaf(t1p[cc], h4.z, q1[2]); q1[3] = fmaf(t1p[cc], h4.w, q1[3]);
            }
        }
        __syncthreads();
        *(float4*)&s_t[(2*ty+0)*64 + 4*tx] = make_float4(q0[0], q0[1], q0[2], q0[3]);
        *(float4*)&s_t[(2*ty+1)*64 + 4*tx] = make_float4(q1[0], q1[1], q1[2], q1[3]);
    }
    __syncthreads();

    // ---- phase 5: scores = (qh + qs.sp + qd.dv)*scale ; softmax in-wave ----
    {
        const int wid = tid >> 6;  // rows wid*8 .. wid*8+7, lane = j
        float relx[8], rely[8], dvx[8], dvy[8], accr[8];
        const float4 oj = *(const float4*)&s_obs[lane * 4];
        #pragma unroll
        for (int k = 0; k < 8; ++k) {
            const int i = i0 + wid * 8 + k;
            const float4 oi = *(const float4*)&s_obs[i * 4];
            relx[k] = oj.x - oi.x;
            rely[k] = oj.y - oi.y;
            dvx[k]  = (oj.z - oi.z) * 4.f;
            dvy[k]  = (oj.w - oi.w) * 4.f;
            accr[k] = 0.f;
        }
        for (int s0 = 0; s0 < 32; s0 += 4) {
            const float4 w0  = *(const float4*)&s_w[s0];
            const float4 w1  = *(const float4*)&s_w[32 + s0];
            const float4 wv0 = *(const float4*)&s_w[64 + s0];
            const float4 wv1 = *(const float4*)&s_w[96 + s0];
            const float4 bs  = *(const float4*)&s_w[128 + s0];
            const float4 bv  = *(const float4*)&s_w[160 + s0];
            #pragma unroll
            for (int k = 0; k < 8; ++k) {
                const int r = wid * 8 + k;
                const float4 qs4 = *(const float4*)&s_qs[r * 32 + s0];
                const float4 qd4 = *(const float4*)&s_qd[r * 32 + s0];
                float acc = accr[k];
                acc = fmaf(qs4.x, fmaxf(fmaf(relx[k], w0.x, fmaf(rely[k], w1.x, bs.x)), 0.f), acc);
                acc = fmaf(qs4.y, fmaxf(fmaf(relx[k], w0.y, fmaf(rely[k], w1.y, bs.y)), 0.f), acc);
                acc = fmaf(qs4.z, fmaxf(fmaf(relx[k], w0.z, fmaf(rely[k], w1.z, bs.z)), 0.f), acc);
                acc = fmaf(qs4.w, fmaxf(fmaf(relx[k], w0.w, fmaf(rely[k], w1.w, bs.w)), 0.f), acc);
                acc = fmaf(qd4.x, fmaxf(fmaf(dvx[k], wv0.x, fmaf(dvy[k], wv1.x, bv.x)), 0.f), acc);
                acc = fmaf(qd4.y, fmaxf(fmaf(dvx[k], wv0.y, fmaf(dvy[k], wv1.y, bv.y)), 0.f), acc);
                acc = fmaf(qd4.z, fmaxf(fmaf(dvx[k], wv0.z, fmaf(dvy[k], wv1.z, bv.z)), 0.f), acc);
                acc = fmaf(qd4.w, fmaxf(fmaf(dvx[k], wv0.w, fmaf(dvy[k], wv1.w, bv.w)), 0.f), acc);
                accr[k] = acc;
            }
        }
        const float scale = 0.08838834764831845f;  // 1/sqrt(128)
        #pragma unroll
        for (int k = 0; k < 8; ++k) {
            const int r = wid * 8 + k;
            const float sc = (s_t[r * 64 + lane] + accr[k]) * scale;
            float m = sc;
            #pragma unroll
            for (int off = 32; off > 0; off >>= 1) m = fmaxf(m, __shfl_xor(m, off, 64));
            const float e = __expf(sc - m);
            float sum = e;
            #pragma unroll
            for (int off = 32; off > 0; off >>= 1) sum += __shfl_xor(sum, off, 64);
            s_t[r * 64 + lane] = e / sum;
        }
    }
    __syncthreads();

    // ---- phase 6: ssp/sdv = sum_j attn*sp/dv ; ah = attn @ hid ----
    {
        // 6a
        const int sx = tid & 7, r6 = tid >> 3;
        const int i = i0 + r6;
        const float4 w0  = *(const float4*)&s_w[4*sx];
        const float4 w1  = *(const float4*)&s_w[32 + 4*sx];
        const float4 wv0 = *(const float4*)&s_w[64 + 4*sx];
        const float4 wv1 = *(const float4*)&s_w[96 + 4*sx];
        const float4 bs  = *(const float4*)&s_w[128 + 4*sx];
        const float4 bv  = *(const float4*)&s_w[160 + 4*sx];
        const float4 oi  = *(const float4*)&s_obs[i * 4];
        float sp0=0, sp1=0, sp2=0, sp3=0, dv0=0, dv1=0, dv2=0, dv3=0;
        for (int j0 = 0; j0 < 64; j0 += 4) {
            const float4 at4 = *(const float4*)&s_t[r6 * 64 + j0];
            const float* atp = (const float*)&at4;
            #pragma unroll
            for (int jj = 0; jj < 4; ++jj) {
                const float4 oj4 = *(const float4*)&s_obs[(j0 + jj) * 4];
                const float a  = atp[jj];
                const float rx = oj4.x - oi.x, ry = oj4.y - oi.y;
                const float dx = (oj4.z - oi.z) * 4.f, dy = (oj4.w - oi.w) * 4.f;
                sp0 = fmaf(a, fmaxf(fmaf(rx, w0.x, fmaf(ry, w1.x, bs.x)), 0.f), sp0);
                sp1 = fmaf(a, fmaxf(fmaf(rx, w0.y, fmaf(ry, w1.y, bs.y)), 0.f), sp1);
                sp2 = fmaf(a, fmaxf(fmaf(rx, w0.z, fmaf(ry, w1.z, bs.z)), 0.f), sp2);
                sp3 = fmaf(a, fmaxf(fmaf(rx, w0.w, fmaf(ry, w1.w, bs.w)), 0.f), sp3);
                dv0 = fmaf(a, fmaxf(fmaf(dx, wv0.x, fmaf(dy, wv1.x, bv.x)), 0.f), dv0);
                dv1 = fmaf(a, fmaxf(fmaf(dx, wv0.y, fmaf(dy, wv1.y, bv.y)), 0.f), dv1);
                dv2 = fmaf(a, fmaxf(fmaf(dx, wv0.z, fmaf(dy, wv1.z, bv.z)), 0.f), dv2);
                dv3 = fmaf(a, fmaxf(fmaf(dx, wv0.w, fmaf(dy, wv1.w, bv.w)), 0.f), dv3);
            }
        }
        *(float4*)&s_ssp[r6 * 32 + 4*sx] = make_float4(sp0, sp1, sp2, sp3);
        *(float4*)&s_sdv[r6 * 32 + 4*sx] = make_float4(dv0, dv1, dv2, dv3);

        // 6b: ah = attn @ hid
        const int ty = tid >> 4, tx = tid & 15;
        float h0[4] = {0,0,0,0}, h1[4] = {0,0,0,0};
        for (int j0 = 0; j0 < 64; j0 += 4) {
            const float4 at0 = *(const float4*)&s_t[(2*ty+0)*64 + j0];
            const float4 at1 = *(const float4*)&s_t[(2*ty+1)*64 + j0];
            const float* a0p = (const float*)&at0;
            const float* a1p = (const float*)&at1;
            #pragma unroll
            for (int jj = 0; jj < 4; ++jj) {
                const float4 h4 = *(const float4*)&s_hid[(j0+jj)*64 + 4*tx];
                h0[0] = fmaf(a0p[jj], h4.x, h0[0]); h0[1] = fmaf(a0p[jj], h4.y, h0[1]);
                h0[2] = fmaf(a0p[jj], h4.z, h0[2]); h0[3] = fmaf(a0p[jj], h4.w, h0[3]);
                h1[0] = fmaf(a1p[jj], h4.x, h1[0]); h1[1] = fmaf(a1p[jj], h4.y, h1[1]);
                h1[2] = fmaf(a1p[jj], h4.z, h1[2]); h1[3] = fmaf(a1p[jj], h4.w, h1[3]);
            }
        }
        *(float4*)&s_ah[(2*ty+0)*64 + 4*tx] = make_float4(h0[0], h0[1], h0[2], h0[3]);
        *(float4*)&s_ah[(2*ty+1)*64 + 4*tx] = make_float4(h1[0], h1[1], h1[2], h1[3]);
    }
    __syncthreads();

    // ---- phase 7: out = ssp@Fsp + sdv@Fdv + ah@Fhid + fb ----
    {
        const int ty = tid >> 4, tx = tid & 15;  // rows 2ty(+1), cols 8tx..8tx+7
        const float4 fba = *(const float4*)&fbv[8*tx];
        const float4 fbb = *(const float4*)&fbv[8*tx + 4];
        float o0a[4] = {fba.x, fba.y, fba.z, fba.w};
        float o0b[4] = {fbb.x, fbb.y, fbb.z, fbb.w};
        float o1a[4] = {fba.x, fba.y, fba.z, fba.w};
        float o1b[4] = {fbb.x, fbb.y, fbb.z, fbb.w};

        #define ACC_TERM(SMAT, LD, FMAT, KMAX)                                        \
        for (int k0 = 0; k0 < (KMAX); k0 += 4) {                                      \
            const float4 a0 = *(const float4*)&SMAT[(2*ty+0)*(LD) + k0];              \
            const float4 a1 = *(const float4*)&SMAT[(2*ty+1)*(LD) + k0];              \
            const float* a0p = (const float*)&a0;                                     \
            const float* a1p = (const float*)&a1;                                     \
            _Pragma("unroll")                                                         \
            for (int kk = 0; kk < 4; ++kk) {                                          \
                const float4 fa = *(const float4*)&FMAT[(k0+kk)*128 + 8*tx];          \
                const float4 fbq = *(const float4*)&FMAT[(k0+kk)*128 + 8*tx + 4];     \
                o0a[0] = fmaf(a0p[kk], fa.x, o0a[0]); o0a[1] = fmaf(a0p[kk], fa.y, o0a[1]); \
                o0a[2] = fmaf(a0p[kk], fa.z, o0a[2]); o0a[3] = fmaf(a0p[kk], fa.w, o0a[3]); \
                o0b[0] = fmaf(a0p[kk], fbq.x, o0b[0]); o0b[1] = fmaf(a0p[kk], fbq.y, o0b[1]); \
                o0b[2] = fmaf(a0p[kk], fbq.z, o0b[2]); o0b[3] = fmaf(a0p[kk], fbq.w, o0b[3]); \
                o1a[0] = fmaf(a1p[kk], fa.x, o1a[0]); o1a[1] = fmaf(a1p[kk], fa.y, o1a[1]); \
                o1a[2] = fmaf(a1p[kk], fa.z, o1a[2]); o1a[3] = fmaf(a1p[kk], fa.w, o1a[3]); \
                o1b[0] = fmaf(a1p[kk], fbq.x, o1b[0]); o1b[1] = fmaf(a1p[kk], fbq.y, o1b[1]); \
                o1b[2] = fmaf(a1p[kk], fbq.z, o1b[2]); o1b[3] = fmaf(a1p[kk], fbq.w, o1b[3]); \
            }                                                                         \
        }
        ACC_TERM(s_ssp, 32, Fsp, 32)
        ACC_TERM(s_sdv, 32, Fdv, 32)
        ACC_TERM(s_ah,  64, Fhid, 64)
        #undef ACC_TERM

        const int gr = (b * 64 + i0 + 2*ty) * 128;
        *(float4*)&out[gr + 8*tx]       = make_float4(o0a[0], o0a[1], o0a[2], o0a[3]);
        *(float4*)&out[gr + 8*tx + 4]   = make_float4(o0b[0], o0b[1], o0b[2], o0b[3]);
        *(float4*)&out[gr + 128 + 8*tx]     = make_float4(o1a[0], o1a[1], o1a[2], o1a[3]);
        *(float4*)&out[gr + 128 + 8*tx + 4] = make_float4(o1b[0], o1b[1], o1b[2], o1b[3]);
    }
}

extern "C" void kernel_launch(void* const* d_in, const int* in_sizes, int n_in,
                              void* d_out, int out_size, void* d_ws, size_t ws_size,
                              hipStream_t stream) {
    const float* hs        = (const float*)d_in[0];
    const float* obs1      = (const float*)d_in[1];
    const float* obs2      = (const float*)d_in[2];
    const float* w_sp      = (const float*)d_in[3];
    const float* b_sp      = (const float*)d_in[4];
    const float* w_vel     = (const float*)d_in[5];
    const float* b_vel     = (const float*)d_in[6];
    const float* w_hid     = (const float*)d_in[7];
    const float* b_hid     = (const float*)d_in[8];
    const float* wq        = (const float*)d_in[9];
    const float* wk        = (const float*)d_in[10];
    const float* wv        = (const float*)d_in[11];
    const float* in_proj_w = (const float*)d_in[12];
    const float* in_proj_b = (const float*)d_in[13];
    const float* mha_out_w = (const float*)d_in[14];
    const float* mha_out_b = (const float*)d_in[15];
    const float* out_w     = (const float*)d_in[16];
    const float* out_b     = (const float*)d_in[17];
    float* ws  = (float*)d_ws;
    float* out = (float*)d_out;

    precompute1<<<512, 128, 0, stream>>>(wq, wk, wv, in_proj_w, mha_out_w, out_w, ws);
    precompute2<<<162, 128, 0, stream>>>(b_sp, b_vel, in_proj_b, mha_out_b, out_w, out_b, ws);
    attn_main<<<256, 256, 0, stream>>>(hs, obs1, obs2, w_sp, b_sp, w_vel, b_vel,
                                       w_hid, b_hid, ws, out);
}